// Round 8
// baseline (392.368 us; speedup 1.0000x reference)
//
#include <hip/hip_runtime.h>

#define KCOLS 7
#define MCOLS 8
#define SW 28         // upper-triangle second-moment count (7*8/2)
#define WPB 22        // words/block: 8 tagged c + 14 packed S pairs
#define LDSCH 768     // 4-row chunks cached in LDS  (3072 rows, 48 KB)
#define CACHECH 1024  // total cached chunks incl. 256 register chunks (4096 rows)
#define NB_PREF 512
#define LROUNDS 12    // local AA rounds per block (zero global syncs)
#define GCAP 8        // HARD cap on global rounds (1 avg + <=6 polish + stop)
#define TAGM 0x7fffffffu

typedef unsigned long long u64;

__device__ __forceinline__ u64 mkword(unsigned tag, float v) {
    return ((u64)tag << 32) | (u64)__float_as_uint(v);
}
__device__ __forceinline__ void st_rel(u64* p, u64 w) {
    __hip_atomic_store(p, w, __ATOMIC_RELAXED, __HIP_MEMORY_SCOPE_AGENT);
}
__device__ __forceinline__ u64 ld_rel(const u64* p) {
    return __hip_atomic_load(p, __ATOMIC_RELAXED, __HIP_MEMORY_SCOPE_AGENT);
}

__device__ __forceinline__ uint32_t pk_bf16(float a, float b) {
    uint32_t ua = __float_as_uint(a), ub = __float_as_uint(b);
    ua += 0x7FFFu + ((ua >> 16) & 1u);
    ub += 0x7FFFu + ((ub >> 16) & 1u);
    return (ua >> 16) | (ub & 0xFFFF0000u);
}
__device__ __forceinline__ void unp(uint32_t u, float& lo, float& hi) {
    lo = __uint_as_float(u << 16);
    hi = __uint_as_float(u & 0xFFFF0000u);
}
__device__ __forceinline__ float rcp_nr(float d) {
    float r = __builtin_amdgcn_rcpf(d);
    return fmaf(fmaf(-d, r, 1.0f), r, r);
}
__device__ __forceinline__ void softmax10(const float* p, float* q, float& sq) {
    float mx = p[0];
#pragma unroll
    for (int j = 1; j < KCOLS; ++j) mx = fmaxf(mx, p[j]);
    float s = 0.0f;
#pragma unroll
    for (int j = 0; j < KCOLS; ++j) s += __expf(p[j] - mx);
    const float ls10 = 10.0f * __logf(s);
    sq = 0.0f;
#pragma unroll
    for (int j = 0; j < KCOLS; ++j) {
        q[j] = __expf(fmaf(10.0f, p[j] - mx, -ls10));
        sq += q[j];
    }
}

__device__ __forceinline__ double red8(double v) {
    v += __shfl_xor(v, 1);
    v += __shfl_xor(v, 2);
    v += __shfl_xor(v, 4);
    return v;
}
__device__ __forceinline__ int and8(int v) {
    v &= __shfl_xor(v, 1);
    v &= __shfl_xor(v, 2);
    v &= __shfl_xor(v, 4);
    return v;
}
__device__ __forceinline__ constexpr int sidx(int j, int k) {
    return j * 7 - (j * (j - 1)) / 2 + (k - j);
}

template <bool WS>
__device__ __forceinline__ void row_acc(const float* q, float rr,
                                        float* acc, float* sacc) {
    float y[KCOLS];
#pragma unroll
    for (int j = 0; j < KCOLS; ++j) { y[j] = q[j] * rr; acc[j] += y[j]; }
    acc[KCOLS] += rr;
    if (WS) {
        int idx = 0;
#pragma unroll
        for (int j = 0; j < KCOLS; ++j)
#pragma unroll
            for (int k = j; k < KCOLS; ++k) {
                sacc[idx] = fmaf(y[j], y[k], sacc[idx]);
                ++idx;
            }
    }
}

__device__ __forceinline__ void setup_chunk(const float4* Pv, size_t f4base,
                                            float* acc, uint4* qq) {
    union { float4 v4[7]; float f[28]; } u;
#pragma unroll
    for (int i = 0; i < 7; ++i) u.v4[i] = Pv[f4base + i];
#pragma unroll
    for (int k = 0; k < 4; ++k) {
        float q[KCOLS], sq;
        softmax10(u.f + k * 7, q, sq);
        qq[k] = make_uint4(pk_bf16(q[0], q[1]), pk_bf16(q[2], q[3]),
                           pk_bf16(q[4], q[5]), pk_bf16(q[6], 1.0f));
        const float rr = rcp_nr(0.125f * (sq + 1.0f));   // fold eval 0, b0=1/8
        row_acc<false>(q, rr, acc, nullptr);
    }
}

template <bool WS>
__device__ __forceinline__ void crow(uint4 u, const float* bf,
                                     float* acc, float* sacc) {
    float f[KCOLS + 1];
    unp(u.x, f[0], f[1]); unp(u.y, f[2], f[3]);
    unp(u.z, f[4], f[5]); unp(u.w, f[6], f[7]);   // f[7] == 1.0
    float dot = f[0] * bf[0];
    dot = fmaf(f[1], bf[1], dot); dot = fmaf(f[2], bf[2], dot);
    dot = fmaf(f[3], bf[3], dot); dot = fmaf(f[4], bf[4], dot);
    dot = fmaf(f[5], bf[5], dot); dot = fmaf(f[6], bf[6], dot);
    dot = fmaf(f[7], bf[7], dot);
    const float rr = rcp_nr(dot);
    row_acc<WS>(f, rr, acc, sacc);
}

template <bool WS>
__device__ __forceinline__ void pass_at_b(const float4* Pv, const float* P,
                                          const uint4* qsh, const uint4* rq,
                                          bool have_reg, int row0, int rows_here,
                                          int nch, int nlds, size_t base4, int tid,
                                          const float* bf, float* a2, float* s2) {
#pragma unroll
    for (int j = 0; j < MCOLS; ++j) a2[j] = 0.0f;
    if (WS) {
#pragma unroll
        for (int m = 0; m < SW; ++m) s2[m] = 0.0f;
    }
#pragma unroll
    for (int jj = 0; jj < 12; ++jj) {
        const int r = tid + 256 * jj;
        if (r < nlds * 4) crow<WS>(qsh[r], bf, a2, s2);
    }
    if (have_reg) {
#pragma unroll
        for (int k = 0; k < 4; ++k) crow<WS>(rq[k], bf, a2, s2);
    }
    for (int c = CACHECH + tid; c < nch; c += 256) {
        union { float4 v4[7]; float f[28]; } u;
#pragma unroll
        for (int i = 0; i < 7; ++i) u.v4[i] = Pv[base4 + (size_t)c * 7 + i];
#pragma unroll
        for (int k = 0; k < 4; ++k) {
            float q[KCOLS], sq;
            softmax10(u.f + k * 7, q, sq);
            float dot = bf[KCOLS];
#pragma unroll
            for (int j = 0; j < KCOLS; ++j) dot = fmaf(q[j], bf[j], dot);
            const float rr = rcp_nr(dot);
            row_acc<WS>(q, rr, a2, s2);
        }
    }
    for (int r = (nch << 2) + tid; r < rows_here; r += 256) {
        float p[KCOLS];
        const float* row = P + (size_t)(row0 + r) * KCOLS;
        for (int j = 0; j < KCOLS; ++j) p[j] = row[j];
        float q[KCOLS], sq;
        softmax10(p, q, sq);
        float dot = bf[KCOLS];
        for (int j = 0; j < KCOLS; ++j) dot = fmaf(q[j], bf[j], dot);
        const float rr = rcp_nr(dot);
        row_acc<WS>(q, rr, a2, s2);
    }
}

__device__ __forceinline__ void final_chunk(const float4* Pv, float4* Ov, size_t f4base,
                                            const float* bpf, const float* bfin) {
    union { float4 v4[7]; float f[28]; } u;
    union { float4 v4[7]; float f[28]; } o;
#pragma unroll
    for (int i = 0; i < 7; ++i) u.v4[i] = Pv[f4base + i];
#pragma unroll
    for (int k = 0; k < 4; ++k) {
        float q[KCOLS], sq;
        softmax10(u.f + k * 7, q, sq);
        float dot = bpf[KCOLS];
#pragma unroll
        for (int j = 0; j < KCOLS; ++j) dot = fmaf(q[j], bpf[j], dot);
        const float rr = rcp_nr(dot);
#pragma unroll
        for (int j = 0; j < KCOLS; ++j) o.f[k * 7 + j] = q[j] * bfin[j] * rr;
    }
#pragma unroll
    for (int i = 0; i < 7; ++i) Ov[f4base + i] = o.v4[i];
}

// v14 = v13 (all-log-space solver) + CAPPED POLISH. R7 showed v13 converges
// at ~0.35-0.4 contraction/round but spends its tail pushing u from 1e-4 to
// 1e-6 accuracy -- invisible in the output (absmax floor 3.9e-3 is the f32
// output-pass quantization, bit-identical across every solver variant since
// R0; plan error ~ entries * rel-b-error ~ 1e-4 at ||F||=1e-5). So:
// (1) natural stop loosened to rn2l <= 1e-10 (||F|| <= 1e-5, 25x margin);
// (2) HARD cap GCAP=8 global rounds; forced stop broadcasts the plain image
// so the (a, b) pairing stays reference-identical. Safety: worst-case
// residual at cap = 3e-2 * 0.4^7 ~ 5e-5 -> plan error ~4e-4, 10x under floor.
__global__ __launch_bounds__(256, 2)
void sinkhorn_v14(const float* __restrict__ P, float* __restrict__ out,
                  u64* __restrict__ pw, u64* __restrict__ bw,
                  int n, int nb, int rpb) {
    const int tid = threadIdx.x, bx = blockIdx.x;
    const int lane = tid & 63, wv = tid >> 6;
    const double inv_n = 1.0 / (double)n;
    const double fi = 1.0 / 1.1;  // GAMMA/(GAMMA+EPSILON)
    const double Pb[MCOLS] = {0.17, 0.14, 0.15, 0.12, 0.05, 0.13, 0.24, 0.0};

    __shared__ uint4 qsh[LDSCH * 4];     // 48 KB
    __shared__ double wred[4][36];
    __shared__ double carr_sh[MCOLS];
    __shared__ double Ssum_sh[SW];       // global S / n
    __shared__ double h_sh[MCOLS];       // plain image (b-space)
    __shared__ double gu_sh[MCOLS];      // plain image (u-space)
    __shared__ double F_sh[MCOLS];       // log residual gu - u
    __shared__ double bcur_sh[MCOLS];    // current b
    __shared__ double ucur_sh[MCOLS];    // current u = log b
    __shared__ double bcast_sh[MCOLS];
    __shared__ double dl_sh[MCOLS];
    __shared__ double rn2l_sh;
    __shared__ float bl_sh[MCOLS];       // local-phase b / follower poll buffer
    __shared__ float bprev_f_sh[MCOLS], bnew_f_sh[MCOLS];
    __shared__ int stop_sh, ntok_sh;

    const int row0 = bx * rpb;
    int rows_here = n - row0;
    if (rows_here > rpb) rows_here = rpb;
    if (rows_here < 0) rows_here = 0;
    const int nch = rows_here >> 2;
    const int nlds = (nch < LDSCH) ? nch : LDSCH;
    const int ncached = (nch < CACHECH) ? nch : CACHECH;
    const size_t base4 = (size_t)(row0 >> 2) * 7;
    const float4* Pv = (const float4*)P;
    const double inv_rows = 1.0 / (double)(rows_here > 0 ? rows_here : 1);
    u64* myw = pw + (size_t)bx * WPB;

    uint4 rq[4];
    const int crg = LDSCH + tid;
    const bool have_reg = (crg < ncached);

    // ---------------- setup: read P, cache q, fold local eval 0 (b0=1/8) ---
    float a2[MCOLS];
#pragma unroll
    for (int j = 0; j < MCOLS; ++j) a2[j] = 0.0f;

#pragma unroll
    for (int jj = 0; jj < 3; ++jj) {
        const int c = tid + 256 * jj;
        if (c < nlds) {
            uint4 qq[4];
            setup_chunk(Pv, base4 + (size_t)c * 7, a2, qq);
#pragma unroll
            for (int k = 0; k < 4; ++k) qsh[c * 4 + k] = qq[k];
        }
    }
    if (have_reg) setup_chunk(Pv, base4 + (size_t)crg * 7, a2, rq);
    for (int c = CACHECH + tid; c < nch; c += 256) {
        uint4 qq[4];
        setup_chunk(Pv, base4 + (size_t)c * 7, a2, qq);
    }
    for (int r = (nch << 2) + tid; r < rows_here; r += 256) {
        float p[KCOLS];
        const float* row = P + (size_t)(row0 + r) * KCOLS;
        for (int j = 0; j < KCOLS; ++j) p[j] = row[j];
        float q[KCOLS], sq;
        softmax10(p, q, sq);
        const float rr = rcp_nr(0.125f * (sq + 1.0f));
        row_acc<false>(q, rr, a2, nullptr);
    }

    // ---------------- LOCAL PHASE: per-block AA-3 in u = log b -------------
    double ucurL = -2.0794415416798357;   // log(0.125)
    double Pf0 = 0, Pf1 = 0, Pf2 = 0, Pg0 = 0, Pg1 = 0, Pg2 = 0;
    int histk = 0;
    float bloc[MCOLS];

    for (int lr = 0; lr < LROUNDS; ++lr) {
#pragma unroll
        for (int j = 0; j < MCOLS; ++j) {
            float v = a2[j];
#pragma unroll
            for (int off = 32; off > 0; off >>= 1) v += __shfl_down(v, off, 64);
            if (lane == 0) wred[wv][j] = (double)v;
        }
        __syncthreads();
        if (wv == 0 && lane < MCOLS) {
            const int j = lane;
            const double cg = (wred[0][j] + wred[1][j] +
                               wred[2][j] + wred[3][j]) * inv_rows;
            const double g = (j < KCOLS) ? fi * (log(Pb[j]) - log(cg)) : 0.0;
            const double f = (j < KCOLS) ? g - ucurL : 0.0;
            double unext = g;
            if (histk >= 1) {
                const double dF0 = f - Pf0, dG0 = g - Pg0;
                const double dF1 = Pf0 - Pf1, dG1 = Pg0 - Pg1;
                const double dF2 = Pf1 - Pf2, dG2 = Pg1 - Pg2;
                double g0 = 0.0, g1 = 0.0, g2 = 0.0;
                int solved = 0;
                if (histk == 1) {
                    const double A00 = red8(dF0 * dF0);
                    const double r0 = red8(dF0 * f);
                    g0 = r0 / (A00 + 1e-12 * A00 + 1e-300);
                    solved = 1;
                } else if (histk == 2) {
                    double A00 = red8(dF0 * dF0);
                    const double A01 = red8(dF0 * dF1);
                    double A11 = red8(dF1 * dF1);
                    const double r0 = red8(dF0 * f);
                    const double r1 = red8(dF1 * f);
                    const double lam = 1e-12 * (A00 + A11) + 1e-300;
                    A00 += lam; A11 += lam;
                    const double det = A00 * A11 - A01 * A01;
                    if (fabs(det) > 1e-280) {
                        g0 = (r0 * A11 - A01 * r1) / det;
                        g1 = (A00 * r1 - A01 * r0) / det;
                        solved = 1;
                    }
                } else {
                    double A00 = red8(dF0 * dF0);
                    const double A01 = red8(dF0 * dF1);
                    const double A02 = red8(dF0 * dF2);
                    double A11 = red8(dF1 * dF1);
                    const double A12 = red8(dF1 * dF2);
                    double A22 = red8(dF2 * dF2);
                    const double r0 = red8(dF0 * f);
                    const double r1 = red8(dF1 * f);
                    const double r2 = red8(dF2 * f);
                    const double lam = 1e-12 * (A00 + A11 + A22) + 1e-300;
                    A00 += lam; A11 += lam; A22 += lam;
                    const double M00 = A11 * A22 - A12 * A12;
                    const double M01 = A01 * A22 - A12 * A02;
                    const double M02 = A01 * A12 - A11 * A02;
                    const double det = A00 * M00 - A01 * M01 + A02 * M02;
                    if (fabs(det) > 1e-280) {
                        const double M11 = A00 * A22 - A02 * A02;
                        const double M12 = A00 * A12 - A01 * A02;
                        const double M22 = A00 * A11 - A01 * A01;
                        g0 = ( r0 * M00 - r1 * M01 + r2 * M02) / det;
                        g1 = (-r0 * M01 + r1 * M11 - r2 * M12) / det;
                        g2 = ( r0 * M02 - r1 * M12 + r2 * M22) / det;
                        solved = 1;
                    }
                }
                if (solved) {
                    double cand = g - (g0 * dG0 + g1 * dG1 + g2 * dG2);
                    int ok = (j >= KCOLS) ? 1
                             : ((cand == cand) && fabs(cand) < 50.0);
                    ok = and8(ok);
                    if (ok) unext = cand;
                    else histk = 0;
                } else {
                    histk = 0;
                }
            }
            Pf2 = Pf1; Pg2 = Pg1; Pf1 = Pf0; Pg1 = Pg0; Pf0 = f; Pg0 = g;
            histk = (histk < 3) ? histk + 1 : 3;
            if (unext > 60.0) unext = 60.0;
            if (unext < -60.0) unext = -60.0;
            ucurL = unext;
            bl_sh[j] = (j < KCOLS) ? (float)exp(ucurL) : 0.0f;
        }
        __syncthreads();
        if (lr == LROUNDS - 1) break;
#pragma unroll
        for (int j = 0; j < MCOLS; ++j) bloc[j] = bl_sh[j];
        pass_at_b<false>(Pv, P, qsh, rq, have_reg, row0, rows_here,
                         nch, nlds, base4, tid, bloc, a2, nullptr);
    }
    // publish local fixed point b_hat (tag 1)
    if (tid < MCOLS)
        st_rel(myw + tid, mkword(1u, bl_sh[tid]));

    // ---------------- GLOBAL PHASE -----------------------------------------
    float bff[MCOLS], bpf[MCOLS];
#pragma unroll
    for (int j = 0; j < MCOLS; ++j) { bff[j] = 0.125f; bpf[j] = 0.125f; }
    float s2[SW];

    const u64* wp0 = pw + (size_t)tid * WPB;
    const u64* wp1 = pw + (size_t)(tid + 256) * WPB;
    const bool h0 = (tid < nb);
    const bool h1 = (tid + 256 < nb);

    // global AA fallback state in u-space (wave0 lanes 0..7)
    double Gf0 = 0, Gf1 = 0, Gf2 = 0, Gg0 = 0, Gg1 = 0, Gg2 = 0;
    int ghist = 0;

    for (int it = 1; it <= GCAP; ++it) {
        const unsigned want = (unsigned)it;
        int stop;
        if (bx == 0) {
            u64 w0[MCOLS], w1[MCOLS];
            for (;;) {
                unsigned bad = 0;
                if (h0) {
#pragma unroll
                    for (int j = 0; j < MCOLS; ++j) w0[j] = ld_rel(wp0 + j);
                }
                if (h1) {
#pragma unroll
                    for (int j = 0; j < MCOLS; ++j) w1[j] = ld_rel(wp1 + j);
                }
                if (h0) {
#pragma unroll
                    for (int j = 0; j < MCOLS; ++j)
                        bad |= ((unsigned)(w0[j] >> 32)) ^ want;
                }
                if (h1) {
#pragma unroll
                    for (int j = 0; j < MCOLS; ++j)
                        bad |= ((unsigned)(w1[j] >> 32)) ^ want;
                }
                if (!bad) break;
                __builtin_amdgcn_s_sleep(1);
            }
            if (it == 1) {
                // ---- geometric-mean of valid local FPs -> warm start ------
                double sums[MCOLS];
                double cnt = 0.0;
#pragma unroll
                for (int j = 0; j < MCOLS; ++j) sums[j] = 0.0;
                if (h0) {
                    float bv[MCOLS];
                    int ok = 1;
#pragma unroll
                    for (int j = 0; j < MCOLS; ++j) bv[j] = __uint_as_float((unsigned)w0[j]);
#pragma unroll
                    for (int j = 0; j < KCOLS; ++j)
                        ok &= (bv[j] == bv[j]) && bv[j] > 1e-30f && bv[j] < 1e30f;
                    if (ok) {
#pragma unroll
                        for (int j = 0; j < KCOLS; ++j) sums[j] += log((double)bv[j]);
                        cnt += 1.0;
                    }
                }
                if (h1) {
                    float bv[MCOLS];
                    int ok = 1;
#pragma unroll
                    for (int j = 0; j < MCOLS; ++j) bv[j] = __uint_as_float((unsigned)w1[j]);
#pragma unroll
                    for (int j = 0; j < KCOLS; ++j)
                        ok &= (bv[j] == bv[j]) && bv[j] > 1e-30f && bv[j] < 1e30f;
                    if (ok) {
#pragma unroll
                        for (int j = 0; j < KCOLS; ++j) sums[j] += log((double)bv[j]);
                        cnt += 1.0;
                    }
                }
#pragma unroll
                for (int m = 0; m < 9; ++m) {
                    double v = (m < MCOLS) ? sums[m] : cnt;
#pragma unroll
                    for (int off = 32; off > 0; off >>= 1) v += __shfl_down(v, off, 64);
                    if (lane == 0) wred[wv][m] = v;
                }
                __syncthreads();
                if (wv == 0 && lane < MCOLS) {
                    const int j = lane;
                    const double c4 = wred[0][8] + wred[1][8] + wred[2][8] + wred[3][8];
                    const double s4 = wred[0][j] + wred[1][j] + wred[2][j] + wred[3][j];
                    double ub = (c4 >= 1.0) ? s4 / c4 : -1.1;   // log(1/3) fallback
                    if (ub > 60.0) ub = 60.0;
                    if (ub < -60.0) ub = -60.0;
                    const double bb = (j < KCOLS) ? exp(ub) : 0.0;
                    ucur_sh[j] = (j < KCOLS) ? ub : 0.0;
                    bcur_sh[j] = bb;
                    bcast_sh[j] = bb;
                    bnew_f_sh[j] = (float)bb;
                    bprev_f_sh[j] = (float)bb;
                    if (j == 0) stop_sh = 0;
                }
                __syncthreads();
            } else {
                // ---- exact global residual + exact-S log-Newton -----------
                double c8[MCOLS];
#pragma unroll
                for (int j = 0; j < MCOLS; ++j) {
                    double v = 0.0;
                    if (h0) v += (double)__uint_as_float((unsigned)w0[j]);
                    if (h1) v += (double)__uint_as_float((unsigned)w1[j]);
                    c8[j] = v;
                }
                double s28[SW];
#pragma unroll
                for (int m = 0; m < SW; ++m) s28[m] = 0.0;
                if (h0) {
#pragma unroll
                    for (int w = 0; w < 14; ++w) {
                        const u64 sw = ld_rel(wp0 + 8 + w);
                        s28[2 * w]     += (double)__uint_as_float((unsigned)sw);
                        s28[2 * w + 1] += (double)__uint_as_float((unsigned)(sw >> 32));
                    }
                }
                if (h1) {
#pragma unroll
                    for (int w = 0; w < 14; ++w) {
                        const u64 sw = ld_rel(wp1 + 8 + w);
                        s28[2 * w]     += (double)__uint_as_float((unsigned)sw);
                        s28[2 * w + 1] += (double)__uint_as_float((unsigned)(sw >> 32));
                    }
                }
#pragma unroll
                for (int j = 0; j < MCOLS; ++j) {
                    double v = c8[j];
#pragma unroll
                    for (int off = 32; off > 0; off >>= 1) v += __shfl_down(v, off, 64);
                    if (lane == 0) wred[wv][j] = v;
                }
#pragma unroll
                for (int m = 0; m < SW; ++m) {
                    double v = s28[m];
#pragma unroll
                    for (int off = 32; off > 0; off >>= 1) v += __shfl_down(v, off, 64);
                    if (lane == 0) wred[wv][8 + m] = v;
                }
                __syncthreads();
                if (tid < MCOLS)
                    carr_sh[tid] = (wred[0][tid] + wred[1][tid] +
                                    wred[2][tid] + wred[3][tid]) * inv_n;
                else if (tid < 36)
                    Ssum_sh[tid - 8] = (wred[0][tid] + wred[1][tid] +
                                        wred[2][tid] + wred[3][tid]) * inv_n;
                __syncthreads();
                if (wv == 0 && lane < MCOLS) {
                    const int j = lane;
                    double gu = 0.0, h = 0.0;
                    if (j < KCOLS) {
                        gu = fi * (log(Pb[j]) - log(carr_sh[j]));
                        h = exp(gu);
                    }
                    const double Fu = (j < KCOLS) ? gu - ucur_sh[j] : 0.0;
                    h_sh[j] = h;
                    gu_sh[j] = gu;
                    F_sh[j] = Fu;
                    const double rl = red8(Fu * Fu);
                    if (j == 0) rn2l_sh = rl;
                }
                __syncthreads();
                if (tid == 0) {
                    const int st = (rn2l_sh <= 1e-10 || it == GCAP) ? 1 : 0;
                    int ok = 0;
                    if (!st) {
                        // A = I - J_u,  (J_u)_jk = fi * S_jk * b_k / c_j
                        double M[7][8];
                        for (int j = 0; j < 7; ++j) {
                            const double invc = fi / carr_sh[j];
                            for (int k = 0; k < 7; ++k) {
                                const int a = j < k ? j : k;
                                const int b2 = j < k ? k : j;
                                M[j][k] = (j == k ? 1.0 : 0.0) -
                                          invc * Ssum_sh[sidx(a, b2)] * bcur_sh[k];
                            }
                            M[j][7] = F_sh[j];
                        }
                        ok = 1;
                        for (int p = 0; p < 7 && ok; ++p) {
                            int pr = p;
                            double pm = fabs(M[p][p]);
                            for (int r = p + 1; r < 7; ++r) {
                                const double m2 = fabs(M[r][p]);
                                if (m2 > pm) { pm = m2; pr = r; }
                            }
                            if (!(pm > 1e-250)) { ok = 0; break; }
                            if (pr != p)
                                for (int k = p; k < 8; ++k) {
                                    const double t = M[p][k];
                                    M[p][k] = M[pr][k];
                                    M[pr][k] = t;
                                }
                            const double pinv = 1.0 / M[p][p];
                            for (int r = p + 1; r < 7; ++r) {
                                const double f = M[r][p] * pinv;
                                for (int k = p; k < 8; ++k) M[r][k] -= f * M[p][k];
                            }
                        }
                        if (ok) {
                            double dl[7];
                            for (int j = 6; j >= 0; --j) {
                                double s = M[j][7];
                                for (int k = j + 1; k < 7; ++k) s -= M[j][k] * dl[k];
                                dl[j] = s / M[j][j];
                            }
                            for (int j = 0; j < 7; ++j) {
                                if (!(dl[j] == dl[j]) || fabs(dl[j]) > 1e6) {
                                    ok = 0;
                                    break;
                                }
                            }
                            if (ok)
                                for (int j = 0; j < 7; ++j) {
                                    double d = dl[j];
                                    if (d > 1.2) d = 1.2;       // relative damping
                                    if (d < -1.2) d = -1.2;
                                    dl_sh[j] = d;
                                }
                        }
                    }
                    ntok_sh = ok;
                    stop_sh = st;
                }
                __syncthreads();
                // ---- step select (u-space): Newton / AA-3 / plain ---------
                if (wv == 0 && lane < MCOLS) {
                    const int j = lane;
                    const double gu = gu_sh[j];
                    const double f = F_sh[j];
                    double un = gu;                 // plain step default
                    if (stop_sh) {
                        un = gu;                    // plain image at stop
                    } else if (ntok_sh) {
                        un = (j < KCOLS) ? ucur_sh[j] + dl_sh[j] : 0.0;
                    } else if (ghist >= 1) {
                        const double dF0 = f - Gf0, dG0 = gu - Gg0;
                        const double dF1 = Gf0 - Gf1, dG1 = Gg0 - Gg1;
                        const double dF2 = Gf1 - Gf2, dG2 = Gg1 - Gg2;
                        double g0 = 0.0, g1 = 0.0, g2 = 0.0;
                        int solved = 0;
                        if (ghist == 1) {
                            const double A00 = red8(dF0 * dF0);
                            const double r0 = red8(dF0 * f);
                            g0 = r0 / (A00 + 1e-12 * A00 + 1e-300);
                            solved = 1;
                        } else if (ghist == 2) {
                            double A00 = red8(dF0 * dF0);
                            const double A01 = red8(dF0 * dF1);
                            double A11 = red8(dF1 * dF1);
                            const double r0 = red8(dF0 * f);
                            const double r1 = red8(dF1 * f);
                            const double lam = 1e-12 * (A00 + A11) + 1e-300;
                            A00 += lam; A11 += lam;
                            const double det = A00 * A11 - A01 * A01;
                            if (fabs(det) > 1e-280) {
                                g0 = (r0 * A11 - A01 * r1) / det;
                                g1 = (A00 * r1 - A01 * r0) / det;
                                solved = 1;
                            }
                        } else {
                            double A00 = red8(dF0 * dF0);
                            const double A01 = red8(dF0 * dF1);
                            const double A02 = red8(dF0 * dF2);
                            double A11 = red8(dF1 * dF1);
                            const double A12 = red8(dF1 * dF2);
                            double A22 = red8(dF2 * dF2);
                            const double r0 = red8(dF0 * f);
                            const double r1 = red8(dF1 * f);
                            const double r2 = red8(dF2 * f);
                            const double lam = 1e-12 * (A00 + A11 + A22) + 1e-300;
                            A00 += lam; A11 += lam; A22 += lam;
                            const double M00 = A11 * A22 - A12 * A12;
                            const double M01 = A01 * A22 - A12 * A02;
                            const double M02 = A01 * A12 - A11 * A02;
                            const double det = A00 * M00 - A01 * M01 + A02 * M02;
                            if (fabs(det) > 1e-280) {
                                const double M11 = A00 * A22 - A02 * A02;
                                const double M12 = A00 * A12 - A01 * A02;
                                const double M22 = A00 * A11 - A01 * A01;
                                g0 = ( r0 * M00 - r1 * M01 + r2 * M02) / det;
                                g1 = (-r0 * M01 + r1 * M11 - r2 * M12) / det;
                                g2 = ( r0 * M02 - r1 * M12 + r2 * M22) / det;
                                solved = 1;
                            }
                        }
                        if (solved) {
                            double cand = gu - (g0 * dG0 + g1 * dG1 + g2 * dG2);
                            int ok2 = (j >= KCOLS) ? 1
                                      : ((cand == cand) && fabs(cand) < 50.0);
                            ok2 = and8(ok2);
                            if (ok2) un = cand;
                            else ghist = 0;
                        } else {
                            ghist = 0;
                        }
                    }
                    if (un > 60.0) un = 60.0;
                    if (un < -60.0) un = -60.0;
                    const double bn = (j < KCOLS) ? exp(un) : 0.0;
                    // push AA history (valid (u,G(u)) secant data regardless)
                    Gf2 = Gf1; Gg2 = Gg1; Gf1 = Gf0; Gg1 = Gg0; Gf0 = f; Gg0 = gu;
                    ghist = (ghist < 3) ? ghist + 1 : 3;
                    bprev_f_sh[j] = (float)bcur_sh[j];
                    bnew_f_sh[j] = (float)bn;
                    bcast_sh[j] = bn;
                    bcur_sh[j] = bn;
                    ucur_sh[j] = (j < KCOLS) ? un : 0.0;
                }
                __syncthreads();
            }
            stop = stop_sh;
            if (tid < MCOLS)
                st_rel(bw + tid, mkword(want | (stop ? 0x80000000u : 0u),
                                        (float)bcast_sh[tid]));
#pragma unroll
            for (int j = 0; j < MCOLS; ++j) {
                bpf[j] = bprev_f_sh[j];
                bff[j] = bnew_f_sh[j];
            }
        } else {
            if (tid < MCOLS) {
                u64 w;
                while ((unsigned)(((w = ld_rel(bw + tid)) >> 32) & TAGM) != want)
                    __builtin_amdgcn_s_sleep(1);
                bl_sh[tid] = __uint_as_float((unsigned)w);
                if (tid == 0) stop_sh = (int)(w >> 63);
            }
            __syncthreads();
            stop = stop_sh;
#pragma unroll
            for (int j = 0; j < MCOLS; ++j) {
                bpf[j] = bff[j];
                bff[j] = bl_sh[j];
            }
        }
        if (stop) break;

        // ---- compute pass at bff: ALL blocks accumulate c + S -------------
        pass_at_b<true>(Pv, P, qsh, rq, have_reg, row0, rows_here,
                        nch, nlds, base4, tid, bff, a2, s2);
#pragma unroll
        for (int m = 0; m < 36; ++m) {
            float v = (m < MCOLS) ? a2[m] : s2[m - MCOLS];
#pragma unroll
            for (int off = 32; off > 0; off >>= 1) v += __shfl_down(v, off, 64);
            if (lane == 0) wred[wv][m] = (double)v;
        }
        __syncthreads();
        if (tid >= 8 && tid < 22) {
            const int w2 = 8 + 2 * (tid - 8);
            const float s0 = (float)(wred[0][w2] + wred[1][w2] +
                                     wred[2][w2] + wred[3][w2]);
            const float s1 = (float)(wred[0][w2 + 1] + wred[1][w2 + 1] +
                                     wred[2][w2 + 1] + wred[3][w2 + 1]);
            st_rel(myw + tid,
                   ((u64)__float_as_uint(s1) << 32) | (u64)__float_as_uint(s0));
        }
        __syncthreads();   // drains S stores (vmcnt 0) before tag stores
        if (tid < MCOLS)
            st_rel(myw + tid,
                   mkword((unsigned)(it + 1),
                          (float)(wred[0][tid] + wred[1][tid] +
                                  wred[2][tid] + wred[3][tid])));
    }

    // ---------------- final pass: exact f32 q from P, write plan -----------
    float4* Ov = (float4*)out;
    for (int c = tid; c < nch; c += 256)
        final_chunk(Pv, Ov, base4 + (size_t)c * 7, bpf, bff);
    for (int r = (nch << 2) + tid; r < rows_here; r += 256) {
        float p[KCOLS];
        const float* row = P + (size_t)(row0 + r) * KCOLS;
        for (int j = 0; j < KCOLS; ++j) p[j] = row[j];
        float q[KCOLS], sq;
        softmax10(p, q, sq);
        float dot = bpf[KCOLS];
        for (int j = 0; j < KCOLS; ++j) dot = fmaf(q[j], bpf[j], dot);
        const float rr = rcp_nr(dot);
        float* orow = out + (size_t)(row0 + r) * KCOLS;
        for (int j = 0; j < KCOLS; ++j) orow[j] = q[j] * bff[j] * rr;
    }
}

extern "C" void kernel_launch(void* const* d_in, const int* in_sizes, int n_in,
                              void* d_out, int out_size, void* d_ws, size_t ws_size,
                              hipStream_t stream) {
    (void)n_in; (void)out_size;
    const float* P = (const float*)d_in[0];
    float* out = (float*)d_out;
    const int n = in_sizes[0] / KCOLS;

    int dev = 0;
    hipGetDevice(&dev);
    int cus = 0;
    hipDeviceGetAttribute(&cus, hipDeviceAttributeMultiprocessorCount, dev);
    if (cus <= 0) cus = 256;
    int maxb = 0;
    if (hipOccupancyMaxActiveBlocksPerMultiprocessor(&maxb, sinkhorn_v14, 256, 0) != hipSuccess || maxb < 1)
        maxb = 1;

    long long cap = (long long)maxb * cus;
    int nb = NB_PREF;
    if (nb > cap) nb = (int)cap;
    while (nb > 64 &&
           (size_t)(((size_t)nb * WPB + MCOLS) * sizeof(u64)) > ws_size) nb >>= 1;
    if (nb < 2) nb = 2;
    int rpb = (((n + nb - 1) / nb) + 3) & ~3;   // nb=512, n=2^21 -> 4096 exact

    u64* pw = (u64*)d_ws;
    u64* bwv = pw + (size_t)nb * WPB;

    void* args[] = {(void*)&P, (void*)&out, (void*)&pw, (void*)&bwv,
                    (void*)&n, (void*)&nb, (void*)&rpb};
    hipLaunchCooperativeKernel((void*)sinkhorn_v14, dim3(nb), dim3(256),
                               args, 0, stream);
}

// Round 9
// 305.316 us; speedup vs baseline: 1.2851x; 1.2851x over previous
//
#include <hip/hip_runtime.h>

#define KCOLS 7
#define MCOLS 8
#define SW 28         // upper-triangle second-moment count (7*8/2)
#define WPB 22        // words/block: 8 tagged c + 14 packed S pairs
#define LDSCH 768     // 4-row chunks cached in LDS  (3072 rows, 48 KB)
#define CACHECH 1024  // total cached chunks incl. 256 register chunks (4096 rows)
#define NB_PREF 512
#define TAGM 0x7fffffffu

typedef unsigned long long u64;

__device__ __forceinline__ u64 mkword(unsigned tag, float v) {
    return ((u64)tag << 32) | (u64)__float_as_uint(v);
}
__device__ __forceinline__ void st_rel(u64* p, u64 w) {
    __hip_atomic_store(p, w, __ATOMIC_RELAXED, __HIP_MEMORY_SCOPE_AGENT);
}
__device__ __forceinline__ u64 ld_rel(const u64* p) {
    return __hip_atomic_load(p, __ATOMIC_RELAXED, __HIP_MEMORY_SCOPE_AGENT);
}

__device__ __forceinline__ uint32_t pk_bf16(float a, float b) {
    uint32_t ua = __float_as_uint(a), ub = __float_as_uint(b);
    ua += 0x7FFFu + ((ua >> 16) & 1u);
    ub += 0x7FFFu + ((ub >> 16) & 1u);
    return (ua >> 16) | (ub & 0xFFFF0000u);
}
__device__ __forceinline__ void unp(uint32_t u, float& lo, float& hi) {
    lo = __uint_as_float(u << 16);
    hi = __uint_as_float(u & 0xFFFF0000u);
}
__device__ __forceinline__ float rcp_nr(float d) {
    float r = __builtin_amdgcn_rcpf(d);
    return fmaf(fmaf(-d, r, 1.0f), r, r);
}
__device__ __forceinline__ void softmax10(const float* p, float* q, float& sq) {
    float mx = p[0];
#pragma unroll
    for (int j = 1; j < KCOLS; ++j) mx = fmaxf(mx, p[j]);
    float s = 0.0f;
#pragma unroll
    for (int j = 0; j < KCOLS; ++j) s += __expf(p[j] - mx);
    const float ls10 = 10.0f * __logf(s);
    sq = 0.0f;
#pragma unroll
    for (int j = 0; j < KCOLS; ++j) {
        q[j] = __expf(fmaf(10.0f, p[j] - mx, -ls10));
        sq += q[j];
    }
}

__device__ __forceinline__ double red8(double v) {
    v += __shfl_xor(v, 1);
    v += __shfl_xor(v, 2);
    v += __shfl_xor(v, 4);
    return v;
}
__device__ __forceinline__ int and8(int v) {
    v &= __shfl_xor(v, 1);
    v &= __shfl_xor(v, 2);
    v &= __shfl_xor(v, 4);
    return v;
}
__device__ __forceinline__ constexpr int sidx(int j, int k) {
    return j * 7 - (j * (j - 1)) / 2 + (k - j);
}

template <bool WS>
__device__ __forceinline__ void row_acc(const float* q, float rr,
                                        float* acc, float* sacc) {
    float y[KCOLS];
#pragma unroll
    for (int j = 0; j < KCOLS; ++j) { y[j] = q[j] * rr; acc[j] += y[j]; }
    acc[KCOLS] += rr;
    if (WS) {
        int idx = 0;
#pragma unroll
        for (int j = 0; j < KCOLS; ++j)
#pragma unroll
            for (int k = j; k < KCOLS; ++k) {
                sacc[idx] = fmaf(y[j], y[k], sacc[idx]);
                ++idx;
            }
    }
}

__device__ __forceinline__ void setup_chunk(const float4* Pv, size_t f4base,
                                            float* acc, uint4* qq) {
    union { float4 v4[7]; float f[28]; } u;
#pragma unroll
    for (int i = 0; i < 7; ++i) u.v4[i] = Pv[f4base + i];
#pragma unroll
    for (int k = 0; k < 4; ++k) {
        float q[KCOLS], sq;
        softmax10(u.f + k * 7, q, sq);
        qq[k] = make_uint4(pk_bf16(q[0], q[1]), pk_bf16(q[2], q[3]),
                           pk_bf16(q[4], q[5]), pk_bf16(q[6], 1.0f));
        const float rr = rcp_nr(0.125f * (sq + 1.0f));   // fold eval 0, b0=1/8
        row_acc<false>(q, rr, acc, nullptr);
    }
}

template <bool WS>
__device__ __forceinline__ void crow(uint4 u, const float* bf,
                                     float* acc, float* sacc) {
    float f[KCOLS + 1];
    unp(u.x, f[0], f[1]); unp(u.y, f[2], f[3]);
    unp(u.z, f[4], f[5]); unp(u.w, f[6], f[7]);   // f[7] == 1.0
    float dot = f[0] * bf[0];
    dot = fmaf(f[1], bf[1], dot); dot = fmaf(f[2], bf[2], dot);
    dot = fmaf(f[3], bf[3], dot); dot = fmaf(f[4], bf[4], dot);
    dot = fmaf(f[5], bf[5], dot); dot = fmaf(f[6], bf[6], dot);
    dot = fmaf(f[7], bf[7], dot);
    const float rr = rcp_nr(dot);
    row_acc<WS>(f, rr, acc, sacc);
}

template <bool WS>
__device__ __forceinline__ void pass_at_b(const float4* Pv, const float* P,
                                          const uint4* qsh, const uint4* rq,
                                          bool have_reg, int row0, int rows_here,
                                          int nch, int nlds, size_t base4, int tid,
                                          const float* bf, float* a2, float* s2) {
#pragma unroll
    for (int j = 0; j < MCOLS; ++j) a2[j] = 0.0f;
    if (WS) {
#pragma unroll
        for (int m = 0; m < SW; ++m) s2[m] = 0.0f;
    }
#pragma unroll
    for (int jj = 0; jj < 12; ++jj) {
        const int r = tid + 256 * jj;
        if (r < nlds * 4) crow<WS>(qsh[r], bf, a2, s2);
    }
    if (have_reg) {
#pragma unroll
        for (int k = 0; k < 4; ++k) crow<WS>(rq[k], bf, a2, s2);
    }
    for (int c = CACHECH + tid; c < nch; c += 256) {
        union { float4 v4[7]; float f[28]; } u;
#pragma unroll
        for (int i = 0; i < 7; ++i) u.v4[i] = Pv[base4 + (size_t)c * 7 + i];
#pragma unroll
        for (int k = 0; k < 4; ++k) {
            float q[KCOLS], sq;
            softmax10(u.f + k * 7, q, sq);
            float dot = bf[KCOLS];
#pragma unroll
            for (int j = 0; j < KCOLS; ++j) dot = fmaf(q[j], bf[j], dot);
            const float rr = rcp_nr(dot);
            row_acc<WS>(q, rr, a2, s2);
        }
    }
    for (int r = (nch << 2) + tid; r < rows_here; r += 256) {
        float p[KCOLS];
        const float* row = P + (size_t)(row0 + r) * KCOLS;
        for (int j = 0; j < KCOLS; ++j) p[j] = row[j];
        float q[KCOLS], sq;
        softmax10(p, q, sq);
        float dot = bf[KCOLS];
        for (int j = 0; j < KCOLS; ++j) dot = fmaf(q[j], bf[j], dot);
        const float rr = rcp_nr(dot);
        row_acc<WS>(q, rr, a2, s2);
    }
}

__device__ __forceinline__ void final_chunk(const float4* Pv, float4* Ov, size_t f4base,
                                            const float* bpf, const float* bfin) {
    union { float4 v4[7]; float f[28]; } u;
    union { float4 v4[7]; float f[28]; } o;
#pragma unroll
    for (int i = 0; i < 7; ++i) u.v4[i] = Pv[f4base + i];
#pragma unroll
    for (int k = 0; k < 4; ++k) {
        float q[KCOLS], sq;
        softmax10(u.f + k * 7, q, sq);
        float dot = bpf[KCOLS];
#pragma unroll
        for (int j = 0; j < KCOLS; ++j) dot = fmaf(q[j], bpf[j], dot);
        const float rr = rcp_nr(dot);
#pragma unroll
        for (int j = 0; j < KCOLS; ++j) o.f[k * 7 + j] = q[j] * bfin[j] * rr;
    }
#pragma unroll
    for (int i = 0; i < 7; ++i) Ov[f4base + i] = o.v4[i];
}

// v15 = v13/v14 hybrid, built to disambiguate R8's paradoxical regression:
// v14 (strictly fewer rounds than v13) measured SLOWER with identical memory
// counters -- either environment (fresh cold container) or code-gen: the
// compile-time loop bound of 8 invites LLVM to unroll the ~2000-inst global
// loop body, blowing the 32KB I-cache (low-VALUBusy stretch, unchanged
// FETCH/WRITE fits). v15: (1) loop bounds are RUNTIME kernel args (gcap,
// lrounds) + unroll(disable) -- unrolling structurally impossible, semantics
// identical; (2) v13's dual stop restored (b-space 1e-12 OR log 1e-10) --
// earliest-stop of both; (3) lrounds 12->8 (AA-3 on the near-affine log map
// reaches ~1e-3 in <=7 evals; local systematic error << 1.7e-2 averaged
// sampling error of the warm start).
__global__ __launch_bounds__(256, 2)
void sinkhorn_v15(const float* __restrict__ P, float* __restrict__ out,
                  u64* __restrict__ pw, u64* __restrict__ bw,
                  int n, int nb, int rpb, int lrounds, int gcap) {
    const int tid = threadIdx.x, bx = blockIdx.x;
    const int lane = tid & 63, wv = tid >> 6;
    const double inv_n = 1.0 / (double)n;
    const double fi = 1.0 / 1.1;  // GAMMA/(GAMMA+EPSILON)
    const double Pb[MCOLS] = {0.17, 0.14, 0.15, 0.12, 0.05, 0.13, 0.24, 0.0};

    __shared__ uint4 qsh[LDSCH * 4];     // 48 KB
    __shared__ double wred[4][36];
    __shared__ double carr_sh[MCOLS];
    __shared__ double Ssum_sh[SW];       // global S / n
    __shared__ double h_sh[MCOLS];       // plain image (b-space)
    __shared__ double gu_sh[MCOLS];      // plain image (u-space)
    __shared__ double F_sh[MCOLS];       // log residual gu - u
    __shared__ double bcur_sh[MCOLS];    // current b
    __shared__ double ucur_sh[MCOLS];    // current u = log b
    __shared__ double bcast_sh[MCOLS];
    __shared__ double dl_sh[MCOLS];
    __shared__ double rn2_sh, rn2l_sh;
    __shared__ float bl_sh[MCOLS];       // local-phase b / follower poll buffer
    __shared__ float bprev_f_sh[MCOLS], bnew_f_sh[MCOLS];
    __shared__ int stop_sh, ntok_sh;

    const int row0 = bx * rpb;
    int rows_here = n - row0;
    if (rows_here > rpb) rows_here = rpb;
    if (rows_here < 0) rows_here = 0;
    const int nch = rows_here >> 2;
    const int nlds = (nch < LDSCH) ? nch : LDSCH;
    const int ncached = (nch < CACHECH) ? nch : CACHECH;
    const size_t base4 = (size_t)(row0 >> 2) * 7;
    const float4* Pv = (const float4*)P;
    const double inv_rows = 1.0 / (double)(rows_here > 0 ? rows_here : 1);
    u64* myw = pw + (size_t)bx * WPB;

    uint4 rq[4];
    const int crg = LDSCH + tid;
    const bool have_reg = (crg < ncached);

    // ---------------- setup: read P, cache q, fold local eval 0 (b0=1/8) ---
    float a2[MCOLS];
#pragma unroll
    for (int j = 0; j < MCOLS; ++j) a2[j] = 0.0f;

#pragma unroll
    for (int jj = 0; jj < 3; ++jj) {
        const int c = tid + 256 * jj;
        if (c < nlds) {
            uint4 qq[4];
            setup_chunk(Pv, base4 + (size_t)c * 7, a2, qq);
#pragma unroll
            for (int k = 0; k < 4; ++k) qsh[c * 4 + k] = qq[k];
        }
    }
    if (have_reg) setup_chunk(Pv, base4 + (size_t)crg * 7, a2, rq);
    for (int c = CACHECH + tid; c < nch; c += 256) {
        uint4 qq[4];
        setup_chunk(Pv, base4 + (size_t)c * 7, a2, qq);
    }
    for (int r = (nch << 2) + tid; r < rows_here; r += 256) {
        float p[KCOLS];
        const float* row = P + (size_t)(row0 + r) * KCOLS;
        for (int j = 0; j < KCOLS; ++j) p[j] = row[j];
        float q[KCOLS], sq;
        softmax10(p, q, sq);
        const float rr = rcp_nr(0.125f * (sq + 1.0f));
        row_acc<false>(q, rr, a2, nullptr);
    }

    // ---------------- LOCAL PHASE: per-block AA-3 in u = log b -------------
    double ucurL = -2.0794415416798357;   // log(0.125)
    double Pf0 = 0, Pf1 = 0, Pf2 = 0, Pg0 = 0, Pg1 = 0, Pg2 = 0;
    int histk = 0;
    float bloc[MCOLS];

#pragma clang loop unroll(disable)
    for (int lr = 0; lr < lrounds; ++lr) {
#pragma unroll
        for (int j = 0; j < MCOLS; ++j) {
            float v = a2[j];
#pragma unroll
            for (int off = 32; off > 0; off >>= 1) v += __shfl_down(v, off, 64);
            if (lane == 0) wred[wv][j] = (double)v;
        }
        __syncthreads();
        if (wv == 0 && lane < MCOLS) {
            const int j = lane;
            const double cg = (wred[0][j] + wred[1][j] +
                               wred[2][j] + wred[3][j]) * inv_rows;
            const double g = (j < KCOLS) ? fi * (log(Pb[j]) - log(cg)) : 0.0;
            const double f = (j < KCOLS) ? g - ucurL : 0.0;
            double unext = g;
            if (histk >= 1) {
                const double dF0 = f - Pf0, dG0 = g - Pg0;
                const double dF1 = Pf0 - Pf1, dG1 = Pg0 - Pg1;
                const double dF2 = Pf1 - Pf2, dG2 = Pg1 - Pg2;
                double g0 = 0.0, g1 = 0.0, g2 = 0.0;
                int solved = 0;
                if (histk == 1) {
                    const double A00 = red8(dF0 * dF0);
                    const double r0 = red8(dF0 * f);
                    g0 = r0 / (A00 + 1e-12 * A00 + 1e-300);
                    solved = 1;
                } else if (histk == 2) {
                    double A00 = red8(dF0 * dF0);
                    const double A01 = red8(dF0 * dF1);
                    double A11 = red8(dF1 * dF1);
                    const double r0 = red8(dF0 * f);
                    const double r1 = red8(dF1 * f);
                    const double lam = 1e-12 * (A00 + A11) + 1e-300;
                    A00 += lam; A11 += lam;
                    const double det = A00 * A11 - A01 * A01;
                    if (fabs(det) > 1e-280) {
                        g0 = (r0 * A11 - A01 * r1) / det;
                        g1 = (A00 * r1 - A01 * r0) / det;
                        solved = 1;
                    }
                } else {
                    double A00 = red8(dF0 * dF0);
                    const double A01 = red8(dF0 * dF1);
                    const double A02 = red8(dF0 * dF2);
                    double A11 = red8(dF1 * dF1);
                    const double A12 = red8(dF1 * dF2);
                    double A22 = red8(dF2 * dF2);
                    const double r0 = red8(dF0 * f);
                    const double r1 = red8(dF1 * f);
                    const double r2 = red8(dF2 * f);
                    const double lam = 1e-12 * (A00 + A11 + A22) + 1e-300;
                    A00 += lam; A11 += lam; A22 += lam;
                    const double M00 = A11 * A22 - A12 * A12;
                    const double M01 = A01 * A22 - A12 * A02;
                    const double M02 = A01 * A12 - A11 * A02;
                    const double det = A00 * M00 - A01 * M01 + A02 * M02;
                    if (fabs(det) > 1e-280) {
                        const double M11 = A00 * A22 - A02 * A02;
                        const double M12 = A00 * A12 - A01 * A02;
                        const double M22 = A00 * A11 - A01 * A01;
                        g0 = ( r0 * M00 - r1 * M01 + r2 * M02) / det;
                        g1 = (-r0 * M01 + r1 * M11 - r2 * M12) / det;
                        g2 = ( r0 * M02 - r1 * M12 + r2 * M22) / det;
                        solved = 1;
                    }
                }
                if (solved) {
                    double cand = g - (g0 * dG0 + g1 * dG1 + g2 * dG2);
                    int ok = (j >= KCOLS) ? 1
                             : ((cand == cand) && fabs(cand) < 50.0);
                    ok = and8(ok);
                    if (ok) unext = cand;
                    else histk = 0;
                } else {
                    histk = 0;
                }
            }
            Pf2 = Pf1; Pg2 = Pg1; Pf1 = Pf0; Pg1 = Pg0; Pf0 = f; Pg0 = g;
            histk = (histk < 3) ? histk + 1 : 3;
            if (unext > 60.0) unext = 60.0;
            if (unext < -60.0) unext = -60.0;
            ucurL = unext;
            bl_sh[j] = (j < KCOLS) ? (float)exp(ucurL) : 0.0f;
        }
        __syncthreads();
        if (lr == lrounds - 1) break;
#pragma unroll
        for (int j = 0; j < MCOLS; ++j) bloc[j] = bl_sh[j];
        pass_at_b<false>(Pv, P, qsh, rq, have_reg, row0, rows_here,
                         nch, nlds, base4, tid, bloc, a2, nullptr);
    }
    // publish local fixed point b_hat (tag 1)
    if (tid < MCOLS)
        st_rel(myw + tid, mkword(1u, bl_sh[tid]));

    // ---------------- GLOBAL PHASE -----------------------------------------
    float bff[MCOLS], bpf[MCOLS];
#pragma unroll
    for (int j = 0; j < MCOLS; ++j) { bff[j] = 0.125f; bpf[j] = 0.125f; }
    float s2[SW];

    const u64* wp0 = pw + (size_t)tid * WPB;
    const u64* wp1 = pw + (size_t)(tid + 256) * WPB;
    const bool h0 = (tid < nb);
    const bool h1 = (tid + 256 < nb);

    // global AA fallback state in u-space (wave0 lanes 0..7)
    double Gf0 = 0, Gf1 = 0, Gf2 = 0, Gg0 = 0, Gg1 = 0, Gg2 = 0;
    int ghist = 0;

#pragma clang loop unroll(disable)
    for (int it = 1; it <= gcap; ++it) {
        const unsigned want = (unsigned)it;
        int stop;
        if (bx == 0) {
            u64 w0[MCOLS], w1[MCOLS];
            for (;;) {
                unsigned bad = 0;
                if (h0) {
#pragma unroll
                    for (int j = 0; j < MCOLS; ++j) w0[j] = ld_rel(wp0 + j);
                }
                if (h1) {
#pragma unroll
                    for (int j = 0; j < MCOLS; ++j) w1[j] = ld_rel(wp1 + j);
                }
                if (h0) {
#pragma unroll
                    for (int j = 0; j < MCOLS; ++j)
                        bad |= ((unsigned)(w0[j] >> 32)) ^ want;
                }
                if (h1) {
#pragma unroll
                    for (int j = 0; j < MCOLS; ++j)
                        bad |= ((unsigned)(w1[j] >> 32)) ^ want;
                }
                if (!bad) break;
                __builtin_amdgcn_s_sleep(1);
            }
            if (it == 1) {
                // ---- geometric-mean of valid local FPs -> warm start ------
                double sums[MCOLS];
                double cnt = 0.0;
#pragma unroll
                for (int j = 0; j < MCOLS; ++j) sums[j] = 0.0;
                if (h0) {
                    float bv[MCOLS];
                    int ok = 1;
#pragma unroll
                    for (int j = 0; j < MCOLS; ++j) bv[j] = __uint_as_float((unsigned)w0[j]);
#pragma unroll
                    for (int j = 0; j < KCOLS; ++j)
                        ok &= (bv[j] == bv[j]) && bv[j] > 1e-30f && bv[j] < 1e30f;
                    if (ok) {
#pragma unroll
                        for (int j = 0; j < KCOLS; ++j) sums[j] += log((double)bv[j]);
                        cnt += 1.0;
                    }
                }
                if (h1) {
                    float bv[MCOLS];
                    int ok = 1;
#pragma unroll
                    for (int j = 0; j < MCOLS; ++j) bv[j] = __uint_as_float((unsigned)w1[j]);
#pragma unroll
                    for (int j = 0; j < KCOLS; ++j)
                        ok &= (bv[j] == bv[j]) && bv[j] > 1e-30f && bv[j] < 1e30f;
                    if (ok) {
#pragma unroll
                        for (int j = 0; j < KCOLS; ++j) sums[j] += log((double)bv[j]);
                        cnt += 1.0;
                    }
                }
#pragma unroll
                for (int m = 0; m < 9; ++m) {
                    double v = (m < MCOLS) ? sums[m] : cnt;
#pragma unroll
                    for (int off = 32; off > 0; off >>= 1) v += __shfl_down(v, off, 64);
                    if (lane == 0) wred[wv][m] = v;
                }
                __syncthreads();
                if (wv == 0 && lane < MCOLS) {
                    const int j = lane;
                    const double c4 = wred[0][8] + wred[1][8] + wred[2][8] + wred[3][8];
                    const double s4 = wred[0][j] + wred[1][j] + wred[2][j] + wred[3][j];
                    double ub = (c4 >= 1.0) ? s4 / c4 : -1.1;   // log(1/3) fallback
                    if (ub > 60.0) ub = 60.0;
                    if (ub < -60.0) ub = -60.0;
                    const double bb = (j < KCOLS) ? exp(ub) : 0.0;
                    ucur_sh[j] = (j < KCOLS) ? ub : 0.0;
                    bcur_sh[j] = bb;
                    bcast_sh[j] = bb;
                    bnew_f_sh[j] = (float)bb;
                    bprev_f_sh[j] = (float)bb;
                    if (j == 0) stop_sh = 0;
                }
                __syncthreads();
            } else {
                // ---- exact global residual + exact-S log-Newton -----------
                double c8[MCOLS];
#pragma unroll
                for (int j = 0; j < MCOLS; ++j) {
                    double v = 0.0;
                    if (h0) v += (double)__uint_as_float((unsigned)w0[j]);
                    if (h1) v += (double)__uint_as_float((unsigned)w1[j]);
                    c8[j] = v;
                }
                double s28[SW];
#pragma unroll
                for (int m = 0; m < SW; ++m) s28[m] = 0.0;
                if (h0) {
#pragma unroll
                    for (int w = 0; w < 14; ++w) {
                        const u64 sw = ld_rel(wp0 + 8 + w);
                        s28[2 * w]     += (double)__uint_as_float((unsigned)sw);
                        s28[2 * w + 1] += (double)__uint_as_float((unsigned)(sw >> 32));
                    }
                }
                if (h1) {
#pragma unroll
                    for (int w = 0; w < 14; ++w) {
                        const u64 sw = ld_rel(wp1 + 8 + w);
                        s28[2 * w]     += (double)__uint_as_float((unsigned)sw);
                        s28[2 * w + 1] += (double)__uint_as_float((unsigned)(sw >> 32));
                    }
                }
#pragma unroll
                for (int j = 0; j < MCOLS; ++j) {
                    double v = c8[j];
#pragma unroll
                    for (int off = 32; off > 0; off >>= 1) v += __shfl_down(v, off, 64);
                    if (lane == 0) wred[wv][j] = v;
                }
#pragma unroll
                for (int m = 0; m < SW; ++m) {
                    double v = s28[m];
#pragma unroll
                    for (int off = 32; off > 0; off >>= 1) v += __shfl_down(v, off, 64);
                    if (lane == 0) wred[wv][8 + m] = v;
                }
                __syncthreads();
                if (tid < MCOLS)
                    carr_sh[tid] = (wred[0][tid] + wred[1][tid] +
                                    wred[2][tid] + wred[3][tid]) * inv_n;
                else if (tid < 36)
                    Ssum_sh[tid - 8] = (wred[0][tid] + wred[1][tid] +
                                        wred[2][tid] + wred[3][tid]) * inv_n;
                __syncthreads();
                if (wv == 0 && lane < MCOLS) {
                    const int j = lane;
                    double gu = 0.0, h = 0.0;
                    if (j < KCOLS) {
                        gu = fi * (log(Pb[j]) - log(carr_sh[j]));
                        h = exp(gu);
                    }
                    const double Fu = (j < KCOLS) ? gu - ucur_sh[j] : 0.0;
                    const double Fb = (j < KCOLS) ? h - bcur_sh[j] : 0.0;
                    h_sh[j] = h;
                    gu_sh[j] = gu;
                    F_sh[j] = Fu;
                    const double ra = red8(Fb * Fb);
                    const double rl = red8(Fu * Fu);
                    if (j == 0) { rn2_sh = ra; rn2l_sh = rl; }
                }
                __syncthreads();
                if (tid == 0) {
                    const int st = (rn2_sh <= 1e-12 || rn2l_sh <= 1e-10 ||
                                    it == gcap) ? 1 : 0;
                    int ok = 0;
                    if (!st) {
                        // A = I - J_u,  (J_u)_jk = fi * S_jk * b_k / c_j
                        double M[7][8];
                        for (int j = 0; j < 7; ++j) {
                            const double invc = fi / carr_sh[j];
                            for (int k = 0; k < 7; ++k) {
                                const int a = j < k ? j : k;
                                const int b2 = j < k ? k : j;
                                M[j][k] = (j == k ? 1.0 : 0.0) -
                                          invc * Ssum_sh[sidx(a, b2)] * bcur_sh[k];
                            }
                            M[j][7] = F_sh[j];
                        }
                        ok = 1;
                        for (int p = 0; p < 7 && ok; ++p) {
                            int pr = p;
                            double pm = fabs(M[p][p]);
                            for (int r = p + 1; r < 7; ++r) {
                                const double m2 = fabs(M[r][p]);
                                if (m2 > pm) { pm = m2; pr = r; }
                            }
                            if (!(pm > 1e-250)) { ok = 0; break; }
                            if (pr != p)
                                for (int k = p; k < 8; ++k) {
                                    const double t = M[p][k];
                                    M[p][k] = M[pr][k];
                                    M[pr][k] = t;
                                }
                            const double pinv = 1.0 / M[p][p];
                            for (int r = p + 1; r < 7; ++r) {
                                const double f = M[r][p] * pinv;
                                for (int k = p; k < 8; ++k) M[r][k] -= f * M[p][k];
                            }
                        }
                        if (ok) {
                            double dl[7];
                            for (int j = 6; j >= 0; --j) {
                                double s = M[j][7];
                                for (int k = j + 1; k < 7; ++k) s -= M[j][k] * dl[k];
                                dl[j] = s / M[j][j];
                            }
                            for (int j = 0; j < 7; ++j) {
                                if (!(dl[j] == dl[j]) || fabs(dl[j]) > 1e6) {
                                    ok = 0;
                                    break;
                                }
                            }
                            if (ok)
                                for (int j = 0; j < 7; ++j) {
                                    double d = dl[j];
                                    if (d > 1.2) d = 1.2;       // relative damping
                                    if (d < -1.2) d = -1.2;
                                    dl_sh[j] = d;
                                }
                        }
                    }
                    ntok_sh = ok;
                    stop_sh = st;
                }
                __syncthreads();
                // ---- step select (u-space): Newton / AA-3 / plain ---------
                if (wv == 0 && lane < MCOLS) {
                    const int j = lane;
                    const double gu = gu_sh[j];
                    const double f = F_sh[j];
                    double un = gu;                 // plain step default
                    if (stop_sh) {
                        un = gu;                    // plain image at stop
                    } else if (ntok_sh) {
                        un = (j < KCOLS) ? ucur_sh[j] + dl_sh[j] : 0.0;
                    } else if (ghist >= 1) {
                        const double dF0 = f - Gf0, dG0 = gu - Gg0;
                        const double dF1 = Gf0 - Gf1, dG1 = Gg0 - Gg1;
                        const double dF2 = Gf1 - Gf2, dG2 = Gg1 - Gg2;
                        double g0 = 0.0, g1 = 0.0, g2 = 0.0;
                        int solved = 0;
                        if (ghist == 1) {
                            const double A00 = red8(dF0 * dF0);
                            const double r0 = red8(dF0 * f);
                            g0 = r0 / (A00 + 1e-12 * A00 + 1e-300);
                            solved = 1;
                        } else if (ghist == 2) {
                            double A00 = red8(dF0 * dF0);
                            const double A01 = red8(dF0 * dF1);
                            double A11 = red8(dF1 * dF1);
                            const double r0 = red8(dF0 * f);
                            const double r1 = red8(dF1 * f);
                            const double lam = 1e-12 * (A00 + A11) + 1e-300;
                            A00 += lam; A11 += lam;
                            const double det = A00 * A11 - A01 * A01;
                            if (fabs(det) > 1e-280) {
                                g0 = (r0 * A11 - A01 * r1) / det;
                                g1 = (A00 * r1 - A01 * r0) / det;
                                solved = 1;
                            }
                        } else {
                            double A00 = red8(dF0 * dF0);
                            const double A01 = red8(dF0 * dF1);
                            const double A02 = red8(dF0 * dF2);
                            double A11 = red8(dF1 * dF1);
                            const double A12 = red8(dF1 * dF2);
                            double A22 = red8(dF2 * dF2);
                            const double r0 = red8(dF0 * f);
                            const double r1 = red8(dF1 * f);
                            const double r2 = red8(dF2 * f);
                            const double lam = 1e-12 * (A00 + A11 + A22) + 1e-300;
                            A00 += lam; A11 += lam; A22 += lam;
                            const double M00 = A11 * A22 - A12 * A12;
                            const double M01 = A01 * A22 - A12 * A02;
                            const double M02 = A01 * A12 - A11 * A02;
                            const double det = A00 * M00 - A01 * M01 + A02 * M02;
                            if (fabs(det) > 1e-280) {
                                const double M11 = A00 * A22 - A02 * A02;
                                const double M12 = A00 * A12 - A01 * A02;
                                const double M22 = A00 * A11 - A01 * A01;
                                g0 = ( r0 * M00 - r1 * M01 + r2 * M02) / det;
                                g1 = (-r0 * M01 + r1 * M11 - r2 * M12) / det;
                                g2 = ( r0 * M02 - r1 * M12 + r2 * M22) / det;
                                solved = 1;
                            }
                        }
                        if (solved) {
                            double cand = gu - (g0 * dG0 + g1 * dG1 + g2 * dG2);
                            int ok2 = (j >= KCOLS) ? 1
                                      : ((cand == cand) && fabs(cand) < 50.0);
                            ok2 = and8(ok2);
                            if (ok2) un = cand;
                            else ghist = 0;
                        } else {
                            ghist = 0;
                        }
                    }
                    if (un > 60.0) un = 60.0;
                    if (un < -60.0) un = -60.0;
                    const double bn = (j < KCOLS) ? exp(un) : 0.0;
                    // push AA history (valid (u,G(u)) secant data regardless)
                    Gf2 = Gf1; Gg2 = Gg1; Gf1 = Gf0; Gg1 = Gg0; Gf0 = f; Gg0 = gu;
                    ghist = (ghist < 3) ? ghist + 1 : 3;
                    bprev_f_sh[j] = (float)bcur_sh[j];
                    bnew_f_sh[j] = (float)bn;
                    bcast_sh[j] = bn;
                    bcur_sh[j] = bn;
                    ucur_sh[j] = (j < KCOLS) ? un : 0.0;
                }
                __syncthreads();
            }
            stop = stop_sh;
            if (tid < MCOLS)
                st_rel(bw + tid, mkword(want | (stop ? 0x80000000u : 0u),
                                        (float)bcast_sh[tid]));
#pragma unroll
            for (int j = 0; j < MCOLS; ++j) {
                bpf[j] = bprev_f_sh[j];
                bff[j] = bnew_f_sh[j];
            }
        } else {
            if (tid < MCOLS) {
                u64 w;
                while ((unsigned)(((w = ld_rel(bw + tid)) >> 32) & TAGM) != want)
                    __builtin_amdgcn_s_sleep(1);
                bl_sh[tid] = __uint_as_float((unsigned)w);
                if (tid == 0) stop_sh = (int)(w >> 63);
            }
            __syncthreads();
            stop = stop_sh;
#pragma unroll
            for (int j = 0; j < MCOLS; ++j) {
                bpf[j] = bff[j];
                bff[j] = bl_sh[j];
            }
        }
        if (stop) break;

        // ---- compute pass at bff: ALL blocks accumulate c + S -------------
        pass_at_b<true>(Pv, P, qsh, rq, have_reg, row0, rows_here,
                        nch, nlds, base4, tid, bff, a2, s2);
#pragma unroll
        for (int m = 0; m < 36; ++m) {
            float v = (m < MCOLS) ? a2[m] : s2[m - MCOLS];
#pragma unroll
            for (int off = 32; off > 0; off >>= 1) v += __shfl_down(v, off, 64);
            if (lane == 0) wred[wv][m] = (double)v;
        }
        __syncthreads();
        if (tid >= 8 && tid < 22) {
            const int w2 = 8 + 2 * (tid - 8);
            const float s0 = (float)(wred[0][w2] + wred[1][w2] +
                                     wred[2][w2] + wred[3][w2]);
            const float s1 = (float)(wred[0][w2 + 1] + wred[1][w2 + 1] +
                                     wred[2][w2 + 1] + wred[3][w2 + 1]);
            st_rel(myw + tid,
                   ((u64)__float_as_uint(s1) << 32) | (u64)__float_as_uint(s0));
        }
        __syncthreads();   // drains S stores (vmcnt 0) before tag stores
        if (tid < MCOLS)
            st_rel(myw + tid,
                   mkword((unsigned)(it + 1),
                          (float)(wred[0][tid] + wred[1][tid] +
                                  wred[2][tid] + wred[3][tid])));
    }

    // ---------------- final pass: exact f32 q from P, write plan -----------
    float4* Ov = (float4*)out;
    for (int c = tid; c < nch; c += 256)
        final_chunk(Pv, Ov, base4 + (size_t)c * 7, bpf, bff);
    for (int r = (nch << 2) + tid; r < rows_here; r += 256) {
        float p[KCOLS];
        const float* row = P + (size_t)(row0 + r) * KCOLS;
        for (int j = 0; j < KCOLS; ++j) p[j] = row[j];
        float q[KCOLS], sq;
        softmax10(p, q, sq);
        float dot = bpf[KCOLS];
        for (int j = 0; j < KCOLS; ++j) dot = fmaf(q[j], bpf[j], dot);
        const float rr = rcp_nr(dot);
        float* orow = out + (size_t)(row0 + r) * KCOLS;
        for (int j = 0; j < KCOLS; ++j) orow[j] = q[j] * bff[j] * rr;
    }
}

extern "C" void kernel_launch(void* const* d_in, const int* in_sizes, int n_in,
                              void* d_out, int out_size, void* d_ws, size_t ws_size,
                              hipStream_t stream) {
    (void)n_in; (void)out_size;
    const float* P = (const float*)d_in[0];
    float* out = (float*)d_out;
    const int n = in_sizes[0] / KCOLS;

    int dev = 0;
    hipGetDevice(&dev);
    int cus = 0;
    hipDeviceGetAttribute(&cus, hipDeviceAttributeMultiprocessorCount, dev);
    if (cus <= 0) cus = 256;
    int maxb = 0;
    if (hipOccupancyMaxActiveBlocksPerMultiprocessor(&maxb, sinkhorn_v15, 256, 0) != hipSuccess || maxb < 1)
        maxb = 1;

    long long cap = (long long)maxb * cus;
    int nb = NB_PREF;
    if (nb > cap) nb = (int)cap;
    while (nb > 64 &&
           (size_t)(((size_t)nb * WPB + MCOLS) * sizeof(u64)) > ws_size) nb >>= 1;
    if (nb < 2) nb = 2;
    int rpb = (((n + nb - 1) / nb) + 3) & ~3;   // nb=512, n=2^21 -> 4096 exact
    int lrounds = 8;
    int gcap = 8;

    u64* pw = (u64*)d_ws;
    u64* bwv = pw + (size_t)nb * WPB;

    void* args[] = {(void*)&P, (void*)&out, (void*)&pw, (void*)&bwv,
                    (void*)&n, (void*)&nb, (void*)&rpb,
                    (void*)&lrounds, (void*)&gcap};
    hipLaunchCooperativeKernel((void*)sinkhorn_v15, dim3(nb), dim3(256),
                               args, 0, stream);
}